// Round 5
// baseline (134.448 us; speedup 1.0000x reference)
//
#include <hip/hip_runtime.h>
#include <math.h>

#define BB 8
#define TT 4096
#define DD 2048
#define THREADS 512           // 8 waves; wave w owns batch row b=w
#define CHUNKS 8              // DD / (64 lanes * 4 floats)

typedef float v4f __attribute__((ext_vector_type(4)));

__device__ __forceinline__ float gelu_fast(float x) {
    // gelu(x) = x * sigmoid(2c*(x + 0.044715 x^3)), c = sqrt(2/pi)
    // e = exp(-(c1*x + c2*x^3)); y = x / (1 + e), rcp via v_rcp_f32 (~1 ulp,
    // threshold is 0.104 abs so plenty). Saturates correctly at both ends.
    const float c1 = 1.5957691216057308f;    // 2c
    const float c2 = 0.07135481282556483f;   // 2c*0.044715
    float x2 = x * x;
    float tt = fmaf(c2, x2, c1);
    float e  = __expf(-x * tt);
    return x * __builtin_amdgcn_rcpf(1.0f + e);
}

__global__ __launch_bounds__(THREADS, 8) void gelu275_fused(
    const float* __restrict__ x,          // [B,T,D]
    const float* __restrict__ log_k_pos,  // [1]
    const float* __restrict__ pos_buf,    // [T,D]
    const float* __restrict__ pos_facil,  // [T]
    float* __restrict__ out)              // [B,T,D]
{
    const int t    = blockIdx.x;
    const int tid  = threadIdx.x;
    const int lane = tid & 63;
    const int wave = tid >> 6;            // == batch row b

    __shared__ float s_dot[BB];
    __shared__ float s_yn2[BB];
    __shared__ float s_pn2;

    const float* xrow = x       + ((size_t)wave * TT + t) * DD;
    const float* prow = pos_buf + (size_t)t * DD;
    const int    base = lane * 4;

    // ---- Pass 1: stream chunks, accumulate dot / |y|^2 / |p|^2 (y not kept) ----
    float dot = 0.0f, yn2 = 0.0f, pn2 = 0.0f;
#pragma unroll
    for (int c = 0; c < CHUNKS; ++c) {
        const v4f xv = *reinterpret_cast<const v4f*>(xrow + c * 256 + base);
        const v4f pv = *reinterpret_cast<const v4f*>(prow + c * 256 + base);
        const float y0 = gelu_fast(xv.x);
        const float y1 = gelu_fast(xv.y);
        const float y2 = gelu_fast(xv.z);
        const float y3 = gelu_fast(xv.w);
        dot += y0 * pv.x + y1 * pv.y + y2 * pv.z + y3 * pv.w;
        yn2 += y0 * y0 + y1 * y1 + y2 * y2 + y3 * y3;
        pn2 += pv.x * pv.x + pv.y * pv.y + pv.z * pv.z + pv.w * pv.w;
    }

    // ---- wave butterfly (3 values x 6 rounds) ----
#pragma unroll
    for (int off = 32; off; off >>= 1) {
        dot += __shfl_xor(dot, off);
        yn2 += __shfl_xor(yn2, off);
        pn2 += __shfl_xor(pn2, off);
    }
    if (lane == 0) {
        s_dot[wave] = dot;
        s_yn2[wave] = yn2;
        if (wave == 0) s_pn2 = pn2;
    }
    __syncthreads();

    // ---- gate from the 17 LDS scalars (computed redundantly per thread) ----
    const float kp = fminf(fmaxf(__expf(log_k_pos[0]), 0.01f), 5.0f);
    const float pn = fmaxf(sqrtf(s_pn2), 1e-12f);

    float simsum = 0.0f;
    float simw   = 0.0f;
#pragma unroll
    for (int b = 0; b < BB; ++b) {
        const float s = s_dot[b] *
            __builtin_amdgcn_rcpf(fmaxf(sqrtf(s_yn2[b]), 1e-12f) * pn);
        simsum += s;
        if (b == wave) simw = s;
    }
    const bool  fire  = (simsum * (1.0f / BB)) > 0.85f;
    const float pf    = pos_facil[t];
    const float facil = fire ? fminf(pf * 2.0f, 16.0f) : pf;
    const float g     = fminf(1.0f + kp * (facil - 1.0f) * simw, 8.0f);

    // ---- Pass 2: re-read x (L2/L3-hot), recompute gelu, gated store ----
    float* orow = out + ((size_t)wave * TT + t) * DD;
#pragma unroll
    for (int c = 0; c < CHUNKS; ++c) {
        const v4f xv = *reinterpret_cast<const v4f*>(xrow + c * 256 + base);
        v4f o;
        o.x = gelu_fast(xv.x) * g;
        o.y = gelu_fast(xv.y) * g;
        o.z = gelu_fast(xv.z) * g;
        o.w = gelu_fast(xv.w) * g;
        *reinterpret_cast<v4f*>(orow + c * 256 + base) = o;
    }
}

extern "C" void kernel_launch(void* const* d_in, const int* in_sizes, int n_in,
                              void* d_out, int out_size, void* d_ws, size_t ws_size,
                              hipStream_t stream) {
    const float* x          = (const float*)d_in[0];
    const float* log_k_pos  = (const float*)d_in[1];
    const float* pos_buf    = (const float*)d_in[2];
    const float* pos_facil  = (const float*)d_in[3];
    float* out              = (float*)d_out;

    dim3 grid(TT);
    dim3 block(THREADS);
    gelu275_fused<<<grid, block, 0, stream>>>(x, log_k_pos, pos_buf, pos_facil, out);
}

// Round 6
// 124.223 us; speedup vs baseline: 1.0823x; 1.0823x over previous
//
#include <hip/hip_runtime.h>
#include <math.h>

#define BB 8
#define TT 4096
#define DD 2048
#define THREADS 512           // 8 waves; wave w owns batch row b=w
#define NT 8                  // t-steps per persistent block
#define NBLK (TT / NT)        // 512 blocks = 2 per CU, all resident

typedef float v4f __attribute__((ext_vector_type(4)));

__device__ __forceinline__ float gelu_fast(float x) {
    // gelu(x) = x * sigmoid(2c*(x + 0.044715 x^3)); saturates correctly.
    const float c1 = 1.5957691216057308f;    // 2*sqrt(2/pi)
    const float c2 = 0.07135481282556483f;   // 2c*0.044715
    float e = __expf(-x * fmaf(c2, x * x, c1));
    return x * __builtin_amdgcn_rcpf(1.0f + e);
}

// One t-step of the pipeline. CUR holds x(t) (loaded one step ago), P holds
// pos(t). Prefetches x(t+1)->NXT at the top and pos(t+1)->P after P dies.
// Raw s_barrier (no vmcnt drain!) keeps the prefetch in flight.
__device__ __forceinline__ void do_step(
    const float* __restrict__ x, const float* __restrict__ pos_buf,
    const float* __restrict__ pos_facil, float* __restrict__ out,
    int t, int par, bool last, int lane, int wave, float kp,
    v4f (&CUR)[8], v4f (&NXT)[8], v4f (&P)[8],
    float (&s_red)[2][17])
{
    const int base = lane * 4;

    // 1) prefetch next x row for this wave (consumed NEXT step)
    if (!last) {
        const float* xr = x + ((size_t)wave * TT + (t + 1)) * DD + base;
#pragma unroll
        for (int c = 0; c < 8; ++c) NXT[c] = *(const v4f*)(xr + c * 256);
    }

    // 2) gelu CUR in place + partial dot / |y|^2 / |p|^2
    float dot = 0.f, yn2 = 0.f, pn2 = 0.f;
#pragma unroll
    for (int c = 0; c < 8; ++c) {
        v4f v = CUR[c];
        v.x = gelu_fast(v.x); v.y = gelu_fast(v.y);
        v.z = gelu_fast(v.z); v.w = gelu_fast(v.w);
        CUR[c] = v;
        const v4f p = P[c];
        dot += v.x * p.x + v.y * p.y + v.z * p.z + v.w * p.w;
        yn2 += v.x * v.x + v.y * v.y + v.z * v.z + v.w * v.w;
        pn2 += p.x * p.x + p.y * p.y + p.z * p.z + p.w * p.w;
    }

    // 3) prefetch next pos row (P regs are dead now; covered by ~800 cy)
    if (!last) {
        const float* pr = pos_buf + (size_t)(t + 1) * DD + base;
#pragma unroll
        for (int c = 0; c < 8; ++c) P[c] = *(const v4f*)(pr + c * 256);
    }

    // 4) wave butterfly (3 values x 6 rounds), cross-wave via LDS
#pragma unroll
    for (int off = 32; off; off >>= 1) {
        dot += __shfl_xor(dot, off);
        yn2 += __shfl_xor(yn2, off);
        pn2 += __shfl_xor(pn2, off);
    }
    if (lane == 0) {
        s_red[par][wave]      = dot;
        s_red[par][BB + wave] = yn2;
        if (wave == 0) s_red[par][16] = pn2;
    }
    // LDS-only drain + RAW barrier: prefetched global loads stay in flight
    // (__syncthreads would emit s_waitcnt vmcnt(0) and kill the pipeline)
    asm volatile("s_waitcnt lgkmcnt(0)" ::: "memory");
    __builtin_amdgcn_s_barrier();
    asm volatile("" ::: "memory");

    // 5) gate from the 17 LDS scalars (redundant per thread)
    const float pnn = fmaxf(sqrtf(s_red[par][16]), 1e-12f);
    float simsum = 0.f, simw = 0.f;
#pragma unroll
    for (int b = 0; b < BB; ++b) {
        const float s = s_red[par][b] *
            __builtin_amdgcn_rcpf(fmaxf(sqrtf(s_red[par][BB + b]), 1e-12f) * pnn);
        simsum += s;
        if (b == wave) simw = s;
    }
    const bool  fire  = (simsum * 0.125f) > 0.85f;
    const float pf    = pos_facil[t];
    const float facil = fire ? fminf(pf * 2.0f, 16.0f) : pf;
    const float g     = fminf(1.0f + kp * (facil - 1.0f) * simw, 8.0f);

    // 6) gated store of this wave's row
    float* orow = out + ((size_t)wave * TT + t) * DD + base;
#pragma unroll
    for (int c = 0; c < 8; ++c) {
        v4f o = CUR[c];
        o.x *= g; o.y *= g; o.z *= g; o.w *= g;
        *(v4f*)(orow + c * 256) = o;
    }
}

__global__ __launch_bounds__(THREADS, 4) void gelu275_fused(
    const float* __restrict__ x,          // [B,T,D]
    const float* __restrict__ log_k_pos,  // [1]
    const float* __restrict__ pos_buf,    // [T,D]
    const float* __restrict__ pos_facil,  // [T]
    float* __restrict__ out)              // [B,T,D]
{
    const int tid  = threadIdx.x;
    const int lane = tid & 63;
    const int wave = tid >> 6;            // == batch row b
    const int t0   = blockIdx.x * NT;

    __shared__ float s_red[2][17];        // parity-double-buffered partials

    const float kp  = fminf(fmaxf(__expf(log_k_pos[0]), 0.01f), 5.0f);
    const int  base = lane * 4;

    v4f A[8], B[8], P[8];

    // prologue: x(t0) -> A, pos(t0) -> P
    {
        const float* xr = x + ((size_t)wave * TT + t0) * DD + base;
#pragma unroll
        for (int c = 0; c < 8; ++c) A[c] = *(const v4f*)(xr + c * 256);
        const float* pr = pos_buf + (size_t)t0 * DD + base;
#pragma unroll
        for (int c = 0; c < 8; ++c) P[c] = *(const v4f*)(pr + c * 256);
    }

#pragma unroll
    for (int i = 0; i < NT; i += 2) {
        do_step(x, pos_buf, pos_facil, out, t0 + i,     0, false,
                lane, wave, kp, A, B, P, s_red);
        do_step(x, pos_buf, pos_facil, out, t0 + i + 1, 1, (i + 2 >= NT),
                lane, wave, kp, B, A, P, s_red);
    }
}

extern "C" void kernel_launch(void* const* d_in, const int* in_sizes, int n_in,
                              void* d_out, int out_size, void* d_ws, size_t ws_size,
                              hipStream_t stream) {
    const float* x          = (const float*)d_in[0];
    const float* log_k_pos  = (const float*)d_in[1];
    const float* pos_buf    = (const float*)d_in[2];
    const float* pos_facil  = (const float*)d_in[3];
    float* out              = (float*)d_out;

    dim3 grid(NBLK);
    dim3 block(THREADS);
    gelu275_fused<<<grid, block, 0, stream>>>(x, log_k_pos, pos_buf, pos_facil, out);
}